// Round 4
// baseline (59.638 us; speedup 1.0000x reference)
//
#include <hip/hip_runtime.h>
#include <math.h>

#define B_ 4
#define Q_ 1024
#define K_ 1024
#define DIN_ 256
#define H_ 64
#define DV_ 128
#define KT 64
#define NS 4               // K-splits
#define SPAN 256           // keys per split = SPAN = 4*KT
#define MASKV -1000000.0f
#define C2LOG2E 2.8853900817779268f   // 2*log2(e): exp(2x)=exp2(C*x)
#define LOG2E 1.4426950408889634f

__device__ __forceinline__ float fexp2(float x) {
#if __has_builtin(__builtin_amdgcn_exp2f)
  return __builtin_amdgcn_exp2f(x);
#else
  return exp2f(x);
#endif
}
__device__ __forceinline__ float frcp(float x) {
#if __has_builtin(__builtin_amdgcn_rcpf)
  return __builtin_amdgcn_rcpf(x);
#else
  return 1.0f / x;
#endif
}
__device__ __forceinline__ float bitsf(unsigned u) { return __uint_as_float(u); }
__device__ __forceinline__ unsigned short f2bf(float f) {  // RNE float->bf16
  unsigned u = __float_as_uint(f);
  return (unsigned short)((u + 0x7FFFu + ((u >> 16) & 1u)) >> 16);
}

// blocks [0,512): row projections EQ/EK = exp2(C * row.W), 16 rows/block
// blocks [512,1024): values -> bf16 (packed, RNE).
__global__ __launch_bounds__(256, 4) void prep_kernel(
    const float* __restrict__ queries, const float* __restrict__ keys,
    const float* __restrict__ values,
    const float* __restrict__ Wq, const float* __restrict__ Wk,
    float* __restrict__ eq, float* __restrict__ ek,
    unsigned short* __restrict__ vb) {
  int bid = blockIdx.x;
  int t = threadIdx.x;
  if (bid >= 512) {
    int i = ((bid - 512) * 256 + t) * 4;     // 512*256*4 = 524288 = B*K*DV
    float4 v = *(const float4*)&values[i];
    ushort4 o;
    o.x = f2bf(v.x); o.y = f2bf(v.y); o.z = f2bf(v.z); o.w = f2bf(v.w);
    *(ushort4*)&vb[i] = o;
    return;
  }
  int w = t >> 6, lane = t & 63;
  int r0 = __builtin_amdgcn_readfirstlane(bid * 16 + w * 4);  // rows r0..r0+3
  const float* src;
  const float* W;
  float* dst;
  if (r0 < B_ * Q_) {
    src = queries + r0 * DIN_; W = Wq; dst = eq + r0 * H_;
  } else {
    int kr = r0 - B_ * Q_;
    src = keys + kr * DIN_; W = Wk; dst = ek + kr * H_;
  }
  float a00 = 0.f, a01 = 0.f, a10 = 0.f, a11 = 0.f;
  float a20 = 0.f, a21 = 0.f, a30 = 0.f, a31 = 0.f;
#pragma unroll 8
  for (int d = 0; d < DIN_; d += 2) {
    float w0 = W[d * H_ + lane];
    float w1 = W[(d + 1) * H_ + lane];
    a00 = fmaf(w0, src[d], a00);             a01 = fmaf(w1, src[d + 1], a01);
    a10 = fmaf(w0, src[DIN_ + d], a10);      a11 = fmaf(w1, src[DIN_ + d + 1], a11);
    a20 = fmaf(w0, src[2 * DIN_ + d], a20);  a21 = fmaf(w1, src[2 * DIN_ + d + 1], a21);
    a30 = fmaf(w0, src[3 * DIN_ + d], a30);  a31 = fmaf(w1, src[3 * DIN_ + d + 1], a31);
  }
  dst[lane]          = fexp2((a00 + a01) * C2LOG2E);
  dst[H_ + lane]     = fexp2((a10 + a11) * C2LOG2E);
  dst[2 * H_ + lane] = fexp2((a20 + a21) * C2LOG2E);
  dst[3 * H_ + lane] = fexp2((a30 + a31) * C2LOG2E);
}

// Flash attention over ONE K-split span. Wave owns 2 queries; lane owns 1 key
// slot. Writes unnormalized partials (m, l, o) for the combine pass.
__global__ __launch_bounds__(256, 4) void attn_kernel(
    const float* __restrict__ eq, const float* __restrict__ ek,
    const unsigned* __restrict__ vb32, const float* __restrict__ wv,
    const int* __restrict__ vlen,
    float* __restrict__ pml, float* __restrict__ po) {
  __shared__ __align__(16) float p_s[4][2][KT];
  int t = threadIdx.x;
  int lane = t & 63;
  int w = t >> 6;
  int bid = blockIdx.x;
  int s = blockIdx.y;
  int b = bid >> 7;                           // 128 blocks per batch
  int q0 = __builtin_amdgcn_readfirstlane(((bid & 127) * 4 + w) * 2);
  int kv = vlen[b];
  int g = b * Q_ + q0;                        // global query row (and g+1)
  int k_lo = s * SPAN;

  if (k_lo >= kv) {                           // inactive split: ml only
    if (lane == 0) {
      *(float2*)&pml[(g * NS + s) * 2] = make_float2(-1e38f, 0.f);
      *(float2*)&pml[((g + 1) * NS + s) * 2] = make_float2(-1e38f, 0.f);
    }
    return;
  }

  const float* eqa = eq + (long)g * H_;
  const float* eqb = eqa + H_;
  const float* ekb = ek + b * K_ * H_;
  const unsigned* vbb = vb32 + b * K_ * (DV_ / 2) + lane;  // + row*64

  float wsum = 0.f;
#pragma unroll
  for (int h = 0; h < H_; ++h) wsum += wv[h];

  float ma = -1e38f, mb = -1e38f, la = 0.f, lb = 0.f;
  float oa0 = 0.f, oa1 = 0.f, ob0 = 0.f, ob1 = 0.f;
  int tile0 = k_lo >> 6;
  int tileE = min((kv + KT - 1) >> 6, tile0 + SPAN / KT);

  for (int tile = tile0; tile < tileE; ++tile) {
    int k0 = tile * KT;
    // ek row for this lane's key -> registers (L2-resident dwordx4 loads)
    const float4* ekr4 = (const float4*)(ekb + (k0 + lane) * H_);
    float ekf[64];
#pragma unroll
    for (int j = 0; j < 16; ++j) {
      float4 tv = ekr4[j];
      ekf[j * 4] = tv.x; ekf[j * 4 + 1] = tv.y;
      ekf[j * 4 + 2] = tv.z; ekf[j * 4 + 3] = tv.w;
    }
    // scores: x = wsum - 2 * sum_h wv[h] / (1 + EQ[h]*EK[h])  (pure compute)
    float aa0 = 0.f, aa1 = 0.f, ab0 = 0.f, ab1 = 0.f;
#pragma unroll
    for (int h = 0; h < H_; ++h) {
      float ekv = ekf[h];
      float wvh = wv[h];
      float ra = frcp(fmaf(ekv, eqa[h], 1.0f));
      float rb = frcp(fmaf(ekv, eqb[h], 1.0f));
      if (h & 1) { aa1 = fmaf(wvh, ra, aa1); ab1 = fmaf(wvh, rb, ab1); }
      else       { aa0 = fmaf(wvh, ra, aa0); ab0 = fmaf(wvh, rb, ab0); }
    }
    float xa = fmaf(-2.f, aa0 + aa1, wsum);
    float xb = fmaf(-2.f, ab0 + ab1, wsum);
    if (k0 + lane >= kv) { xa = MASKV; xb = MASKV; }

    // wave-local online softmax for both queries (interleaved reduces)
    float mta = xa, mtb = xb;
#pragma unroll
    for (int sh = 32; sh >= 1; sh >>= 1) {
      mta = fmaxf(mta, __shfl_xor(mta, sh));
      mtb = fmaxf(mtb, __shfl_xor(mtb, sh));
    }
    float mna = fmaxf(ma, mta), mnb = fmaxf(mb, mtb);
    float pa = fexp2((xa - mna) * LOG2E);
    float pb = fexp2((xb - mnb) * LOG2E);
    float psa = pa, psb = pb;
#pragma unroll
    for (int sh = 32; sh >= 1; sh >>= 1) {
      psa += __shfl_xor(psa, sh);
      psb += __shfl_xor(psb, sh);
    }
    float sca = fexp2((ma - mna) * LOG2E);
    float scb = fexp2((mb - mnb) * LOG2E);
    la = fmaf(la, sca, psa); lb = fmaf(lb, scb, psb);
    ma = mna; mb = mnb;
    oa0 *= sca; oa1 *= sca; ob0 *= scb; ob1 *= scb;
    p_s[w][0][lane] = pa;
    p_s[w][1][lane] = pb;   // same-wave write->read; compiler inserts lgkmcnt

    // PV: p broadcast from wave-private LDS, V as packed bf16 pairs
#pragma unroll 4
    for (int k4 = 0; k4 < KT / 4; ++k4) {
      float4 pa4 = *(const float4*)&p_s[w][0][k4 * 4];
      float4 pb4 = *(const float4*)&p_s[w][1][k4 * 4];
      int r = (k0 + k4 * 4) * (DV_ / 2);
      unsigned vv0 = vbb[r];
      unsigned vv1 = vbb[r + 64];
      unsigned vv2 = vbb[r + 128];
      unsigned vv3 = vbb[r + 192];
      float v00 = bitsf(vv0 << 16), v01 = bitsf(vv0 & 0xFFFF0000u);
      float v10 = bitsf(vv1 << 16), v11 = bitsf(vv1 & 0xFFFF0000u);
      float v20 = bitsf(vv2 << 16), v21 = bitsf(vv2 & 0xFFFF0000u);
      float v30 = bitsf(vv3 << 16), v31 = bitsf(vv3 & 0xFFFF0000u);
      oa0 = fmaf(pa4.x, v00, oa0); oa1 = fmaf(pa4.x, v01, oa1);
      ob0 = fmaf(pb4.x, v00, ob0); ob1 = fmaf(pb4.x, v01, ob1);
      oa0 = fmaf(pa4.y, v10, oa0); oa1 = fmaf(pa4.y, v11, oa1);
      ob0 = fmaf(pb4.y, v10, ob0); ob1 = fmaf(pb4.y, v11, ob1);
      oa0 = fmaf(pa4.z, v20, oa0); oa1 = fmaf(pa4.z, v21, oa1);
      ob0 = fmaf(pb4.z, v20, ob0); ob1 = fmaf(pb4.z, v21, ob1);
      oa0 = fmaf(pa4.w, v30, oa0); oa1 = fmaf(pa4.w, v31, oa1);
      ob0 = fmaf(pb4.w, v30, ob0); ob1 = fmaf(pb4.w, v31, ob1);
    }
  }

  // unnormalized partials
  long pbase = ((long)g * NS + s) * DV_ + lane * 2;
  *(float2*)&po[pbase] = make_float2(oa0, oa1);
  *(float2*)&po[pbase + NS * DV_] = make_float2(ob0, ob1);
  if (lane == 0) {
    *(float2*)&pml[(g * NS + s) * 2] = make_float2(ma, la);
    *(float2*)&pml[((g + 1) * NS + s) * 2] = make_float2(mb, lb);
  }
}

// Merge NS partials per query row: O = sum_s o_s*e^{m_s-M}, L likewise.
__global__ __launch_bounds__(256, 4) void combine_kernel(
    const float* __restrict__ pml, const float* __restrict__ po,
    float* __restrict__ out) {
  int t = threadIdx.x;
  int lane = t & 63;
  int w = t >> 6;
  int qrow = blockIdx.x * 4 + w;
  float m[NS], l[NS];
  float M = -1e38f;
#pragma unroll
  for (int s = 0; s < NS; ++s) {
    float2 v = *(const float2*)&pml[(qrow * NS + s) * 2];
    m[s] = v.x; l[s] = v.y;
    M = fmaxf(M, m[s]);
  }
  float L = 0.f, ax = 0.f, ay = 0.f;
#pragma unroll
  for (int s = 0; s < NS; ++s) {
    if (l[s] > 0.f) {                 // wave-uniform branch
      float wgt = fexp2((m[s] - M) * LOG2E);
      L = fmaf(l[s], wgt, L);
      float2 o2 = *(const float2*)&po[((long)qrow * NS + s) * DV_ + lane * 2];
      ax = fmaf(o2.x, wgt, ax);
      ay = fmaf(o2.y, wgt, ay);
    }
  }
  float inv = frcp(L);
  *(float2*)&out[(long)qrow * DV_ + lane * 2] = make_float2(ax * inv, ay * inv);
}

extern "C" void kernel_launch(void* const* d_in, const int* in_sizes, int n_in,
                              void* d_out, int out_size, void* d_ws, size_t ws_size,
                              hipStream_t stream) {
  const float* queries = (const float*)d_in[0];
  const float* keys    = (const float*)d_in[1];
  const float* values  = (const float*)d_in[2];
  const int*   vl      = (const int*)d_in[3];
  const float* Wq      = (const float*)d_in[4];
  const float* Wk      = (const float*)d_in[5];
  const float* wv      = (const float*)d_in[6];
  float* out = (float*)d_out;

  float* eq = (float*)d_ws;                          // 4096*64 f = 1 MB
  float* ek = eq + (size_t)B_ * Q_ * H_;             // 4096*64 f = 1 MB
  unsigned short* vb = (unsigned short*)(ek + (size_t)B_ * K_ * H_);  // 1 MB
  float* pml = (float*)(vb + (size_t)B_ * K_ * DV_);                  // 128 KB
  float* po = pml + (size_t)B_ * Q_ * NS * 2;                         // 8 MB

  prep_kernel<<<dim3(1024), dim3(256), 0, stream>>>(
      queries, keys, values, Wq, Wk, eq, ek, vb);
  attn_kernel<<<dim3(B_ * (Q_ / 8), NS), dim3(256), 0, stream>>>(
      eq, ek, (const unsigned*)vb, wv, vl, pml, po);
  combine_kernel<<<dim3(B_ * Q_ / 4), dim3(256), 0, stream>>>(pml, po, out);
}